// Round 18
// baseline (205.408 us; speedup 1.0000x reference)
//
#include <hip/hip_runtime.h>
#include <hip/hip_bf16.h>
#include <math.h>

// Problem constants
constexpr int B_ = 8;
constexpr int C_ = 512;
constexpr int M_ = 64;     // C/8
constexpr int N_ = 4096;   // H*W
constexpr int NCHUNK_ = 4; // split-N factor for kx
constexpr float EPS_ = 1e-10f;
constexpr float PARAM_ = 10.0f;

typedef __attribute__((ext_vector_type(4))) float f32x4;
typedef __attribute__((ext_vector_type(8))) short bf16x8;   // 8 bf16 in 4 VGPRs

// elus feature map: t>0 ? 10t+1 : exp(10t)
__device__ __forceinline__ float elus(float t) {
    return (t > 0.f) ? fmaf(PARAM_, t, 1.f) : expf(PARAM_ * t);
}

// fp32 -> bf16 RTNE (compiler-packable)
__device__ __forceinline__ short f2bf(float f) {
    return __builtin_bit_cast(short, __float2bfloat16(f));
}
// bf16 bits -> fp32
__device__ __forceinline__ float bf2f(short s) {
    unsigned u = ((unsigned)(unsigned short)s) << 16;
    return __builtin_bit_cast(float, u);
}

// ---------------------------------------------------------------------------
// Kernel 0: convert the 4 feature weight matrices to bf16 once.
// Wbf layout: [4][M][C]  (0=Wq, 1=Wk1, 2=Wk2, 3=Wk3)
// ---------------------------------------------------------------------------
__global__ __launch_bounds__(256) void prep_w(const float* __restrict__ Wq,
                                              const float* __restrict__ Wk1,
                                              const float* __restrict__ Wk2,
                                              const float* __restrict__ Wk3,
                                              short* __restrict__ Wbf)
{
    int i = blockIdx.x * 256 + threadIdx.x;
    const int MC = M_ * C_;
    if (i < MC) {
        Wbf[i]          = f2bf(Wq[i]);
        Wbf[MC + i]     = f2bf(Wk1[i]);
        Wbf[2 * MC + i] = f2bf(Wk2[i]);
        Wbf[3 * MC + i] = f2bf(Wk3[i]);
    }
}

// ---------------------------------------------------------------------------
// Kernel 1 (MFMA): feature GEMMs, T14 software-pipelined staging.
// blockIdx.y = 0: x -> Q (QT) + K1.  y=1: y -> K2.  y=2: z -> K3.
// Per iteration: barrier -> write held regs to LDS -> barrier -> ISSUE next
// chunk's global loads -> MFMA. Next loads fly during MFMA + next write phase.
// ---------------------------------------------------------------------------
__global__ __launch_bounds__(256) void feat_mfma(
    const float* __restrict__ x, const float* __restrict__ y,
    const float* __restrict__ z, const short* __restrict__ Wbf,
    const float* __restrict__ bq, const float* __restrict__ bk1,
    const float* __restrict__ bk2, const float* __restrict__ bk3,
    short* __restrict__ QT, short* __restrict__ Kbuf3,
    float* __restrict__ Ksumpart)
{
    const int n0 = blockIdx.x * 64;
    const int which = blockIdx.y;       // 0:x->(Q,K1)  1:y->K2  2:z->K3
    const int b  = blockIdx.z;
    const int MC = M_ * C_;

    const float* in = (which == 0) ? x : (which == 1) ? y : z;
    const short* Ws0 = Wbf + (size_t)((which == 0) ? 0 : which + 1) * MC;
    const short* Ws1 = Wbf + (size_t)MC;   // Wk1 (fused path only)

    __shared__ short Wlds[2][64][72];
    __shared__ short Xlds[64][72];

    const int tid  = threadIdx.x;
    const int lane = tid & 63;
    const int w    = tid >> 6;
    const int lrow = lane & 15;
    const int lkg  = lane >> 4;

    const float* inb = in + (size_t)b * C_ * N_;

    f32x4 accA[4] = {{0.f,0.f,0.f,0.f},{0.f,0.f,0.f,0.f},{0.f,0.f,0.f,0.f},{0.f,0.f,0.f,0.f}};
    f32x4 accB[4] = {{0.f,0.f,0.f,0.f},{0.f,0.f,0.f,0.f},{0.f,0.f,0.f,0.f},{0.f,0.f,0.f,0.f}};

    const int kq = tid >> 4;   // 0..15 -> k base kq*4 (X transpose staging)
    const int nq = tid & 15;   // 0..15 -> n base nq*4
    const int wr = tid >> 3, wc8 = (tid & 7) * 8;          // W stage coords (i=0)
    const int wr2 = (tid + 256) >> 3, wc82 = ((tid + 256) & 7) * 8;  // (i=1)

    // prefetch registers
    int4 wreg0a, wreg0b, wreg1a, wreg1b;
    f32x4 xr0, xr1, xr2, xr3;

    auto issueW = [&](int k0) {
        wreg0a = *reinterpret_cast<const int4*>(&Ws0[(size_t)wr * C_ + k0 + wc8]);
        wreg0b = *reinterpret_cast<const int4*>(&Ws0[(size_t)wr2 * C_ + k0 + wc82]);
        if (which == 0) {
            wreg1a = *reinterpret_cast<const int4*>(&Ws1[(size_t)wr * C_ + k0 + wc8]);
            wreg1b = *reinterpret_cast<const int4*>(&Ws1[(size_t)wr2 * C_ + k0 + wc82]);
        }
    };
    auto issueX = [&](int k0) {
        xr0 = *reinterpret_cast<const f32x4*>(&inb[(size_t)(k0 + kq * 4 + 0) * N_ + n0 + nq * 4]);
        xr1 = *reinterpret_cast<const f32x4*>(&inb[(size_t)(k0 + kq * 4 + 1) * N_ + n0 + nq * 4]);
        xr2 = *reinterpret_cast<const f32x4*>(&inb[(size_t)(k0 + kq * 4 + 2) * N_ + n0 + nq * 4]);
        xr3 = *reinterpret_cast<const f32x4*>(&inb[(size_t)(k0 + kq * 4 + 3) * N_ + n0 + nq * 4]);
    };

    issueW(0);
    issueX(0);

    for (int kc = 0; kc < C_ / 64; ++kc) {
        __syncthreads();   // previous chunk's frag reads done — LDS free
        // write held registers to LDS (vmcnt wait lands here)
        *reinterpret_cast<int4*>(&Wlds[0][wr][wc8])   = wreg0a;
        *reinterpret_cast<int4*>(&Wlds[0][wr2][wc82]) = wreg0b;
        if (which == 0) {
            *reinterpret_cast<int4*>(&Wlds[1][wr][wc8])   = wreg1a;
            *reinterpret_cast<int4*>(&Wlds[1][wr2][wc82]) = wreg1b;
        }
        #pragma unroll
        for (int c = 0; c < 4; ++c) {
            short4 s;
            s.x = f2bf(xr0[c]); s.y = f2bf(xr1[c]); s.z = f2bf(xr2[c]); s.w = f2bf(xr3[c]);
            *reinterpret_cast<short4*>(&Xlds[nq * 4 + c][kq * 4]) = s;
        }
        __syncthreads();
        // issue NEXT chunk's loads — they fly during the MFMA below
        if (kc + 1 < C_ / 64) {
            issueW((kc + 1) * 64);
            issueX((kc + 1) * 64);
        }
        #pragma unroll
        for (int ks = 0; ks < 2; ++ks) {
            bf16x8 a0 = *reinterpret_cast<const bf16x8*>(&Wlds[0][w * 16 + lrow][ks * 32 + lkg * 8]);
            bf16x8 a1;
            if (which == 0)
                a1 = *reinterpret_cast<const bf16x8*>(&Wlds[1][w * 16 + lrow][ks * 32 + lkg * 8]);
            #pragma unroll
            for (int ns = 0; ns < 4; ++ns) {
                bf16x8 bx = *reinterpret_cast<const bf16x8*>(&Xlds[ns * 16 + lrow][ks * 32 + lkg * 8]);
                accA[ns] = __builtin_amdgcn_mfma_f32_16x16x32_bf16(a0, bx, accA[ns], 0, 0, 0);
                if (which == 0)
                    accB[ns] = __builtin_amdgcn_mfma_f32_16x16x32_bf16(a1, bx, accB[ns], 0, 0, 0);
            }
        }
    }

    // --- epilogues ---
    auto writeK = [&](const f32x4* acc, const float* bias, int br) {
        short* outb = Kbuf3 + ((size_t)br * B_ + b) * M_ * N_;
        float* ksp  = Ksumpart + ((size_t)br * B_ + b) * 64 * M_;  // [nblk][m]
        #pragma unroll
        for (int r = 0; r < 4; ++r) {
            int m = w * 16 + lkg * 4 + r;
            float bi = bias[m];
            float sv = 0.f;
            #pragma unroll
            for (int ns = 0; ns < 4; ++ns) {
                int n = n0 + ns * 16 + lrow;
                float e = elus(acc[ns][r] + bi);
                outb[(size_t)m * N_ + n] = f2bf(e);
                sv += e;
            }
            sv += __shfl_xor(sv, 1);
            sv += __shfl_xor(sv, 2);
            sv += __shfl_xor(sv, 4);
            sv += __shfl_xor(sv, 8);
            if (lrow == 0)
                ksp[(size_t)blockIdx.x * M_ + m] = sv;
        }
    };

    if (which == 0) {
        short* outb = QT + (size_t)b * N_ * M_;
        int mbase = w * 16 + lkg * 4;
        float bi[4];
        #pragma unroll
        for (int r = 0; r < 4; ++r) bi[r] = bq[mbase + r];
        #pragma unroll
        for (int ns = 0; ns < 4; ++ns) {
            int n = n0 + ns * 16 + lrow;
            short4 s;
            s.x = f2bf(elus(accA[ns][0] + bi[0]));
            s.y = f2bf(elus(accA[ns][1] + bi[1]));
            s.z = f2bf(elus(accA[ns][2] + bi[2]));
            s.w = f2bf(elus(accA[ns][3] + bi[3]));
            *reinterpret_cast<short4*>(&outb[(size_t)n * M_ + mbase]) = s;
        }
        writeK(accB, bk1, 0);
    } else {
        writeK(accA, (which == 1) ? bk2 : bk3, which);
    }
}

// ---------------------------------------------------------------------------
// Kernel 2: Ksum[b][br][m] = sum_nb Ksumpart[br][b][nb][m]  (all branches)
// ---------------------------------------------------------------------------
__global__ __launch_bounds__(256) void ksum_finalize(const float* __restrict__ Ksumpart,
                                                     float* __restrict__ Ksum)
{
    int i = blockIdx.x * 256 + threadIdx.x;   // (br, b, m)
    if (i >= 3 * B_ * M_) return;
    int br = i / (B_ * M_);
    int rem = i - br * (B_ * M_);
    int b = rem >> 6, m = rem & 63;
    const float* ksp = Ksumpart + ((size_t)br * B_ + b) * 64 * M_;
    float s = 0.f;
    #pragma unroll 8
    for (int nb = 0; nb < 64; ++nb) s += ksp[(size_t)nb * M_ + m];
    Ksum[((size_t)b * 3 + br) * M_ + m] = s;
}

// ---------------------------------------------------------------------------
// Kernel 3a (MFMA): split-N partial KX for ALL THREE branches, T14-pipelined.
// ---------------------------------------------------------------------------
__global__ __launch_bounds__(256) void kx3_mfma(const short* __restrict__ Kbuf3,
                                                const float* __restrict__ x,
                                                float* __restrict__ KXpart3)
{
    const int c0 = blockIdx.x * 32;
    const int nc = blockIdx.y;
    const int b  = blockIdx.z;
    const int nbeg = nc * (N_ / NCHUNK_);

    __shared__ short Klds[3][64][72];
    __shared__ short Xlds[32][72];

    const int tid  = threadIdx.x;
    const int lane = tid & 63;
    const int w    = tid >> 6;
    const int lrow = lane & 15;
    const int lkg  = lane >> 4;

    const float* xb = x + ((size_t)b * C_ + c0) * N_;

    f32x4 acc[3][2] = {};

    // staging coordinates
    const int kr1 = tid >> 3, kc81 = (tid & 7) * 8;                 // K stage (i=0)
    const int kr2 = (tid + 256) >> 3, kc82 = ((tid + 256) & 7) * 8; // K stage (i=1)
    const int xr1_ = tid >> 4, xc41 = (tid & 15) * 4;               // X stage (i=0)
    const int xr2_ = (tid + 256) >> 4, xc42 = ((tid + 256) & 15) * 4;

    int4 kreg[3][2];
    float4 xrg0, xrg1;

    auto issueK = [&](int n0) {
        #pragma unroll
        for (int br = 0; br < 3; ++br) {
            const short* kb = Kbuf3 + ((size_t)br * B_ + b) * M_ * N_;
            kreg[br][0] = *reinterpret_cast<const int4*>(&kb[(size_t)kr1 * N_ + n0 + kc81]);
            kreg[br][1] = *reinterpret_cast<const int4*>(&kb[(size_t)kr2 * N_ + n0 + kc82]);
        }
    };
    auto issueX = [&](int n0) {
        xrg0 = *reinterpret_cast<const float4*>(&xb[(size_t)xr1_ * N_ + n0 + xc41]);
        xrg1 = *reinterpret_cast<const float4*>(&xb[(size_t)xr2_ * N_ + n0 + xc42]);
    };

    issueK(nbeg);
    issueX(nbeg);

    for (int it = 0; it < (N_ / NCHUNK_) / 64; ++it) {
        const int n0 = nbeg + it * 64;
        __syncthreads();
        // write held regs
        #pragma unroll
        for (int br = 0; br < 3; ++br) {
            *reinterpret_cast<int4*>(&Klds[br][kr1][kc81]) = kreg[br][0];
            *reinterpret_cast<int4*>(&Klds[br][kr2][kc82]) = kreg[br][1];
        }
        {
            short4 s0, s1;
            s0.x = f2bf(xrg0.x); s0.y = f2bf(xrg0.y); s0.z = f2bf(xrg0.z); s0.w = f2bf(xrg0.w);
            s1.x = f2bf(xrg1.x); s1.y = f2bf(xrg1.y); s1.z = f2bf(xrg1.z); s1.w = f2bf(xrg1.w);
            *reinterpret_cast<short4*>(&Xlds[xr1_][xc41]) = s0;
            *reinterpret_cast<short4*>(&Xlds[xr2_][xc42]) = s1;
        }
        __syncthreads();
        if (it + 1 < (N_ / NCHUNK_) / 64) {
            issueK(n0 + 64);
            issueX(n0 + 64);
        }
        #pragma unroll
        for (int s = 0; s < 2; ++s) {
            bf16x8 b0 = *reinterpret_cast<const bf16x8*>(&Xlds[lrow][s * 32 + lkg * 8]);
            bf16x8 b1 = *reinterpret_cast<const bf16x8*>(&Xlds[16 + lrow][s * 32 + lkg * 8]);
            #pragma unroll
            for (int br = 0; br < 3; ++br) {
                bf16x8 a = *reinterpret_cast<const bf16x8*>(&Klds[br][w * 16 + lrow][s * 32 + lkg * 8]);
                acc[br][0] = __builtin_amdgcn_mfma_f32_16x16x32_bf16(a, b0, acc[br][0], 0, 0, 0);
                acc[br][1] = __builtin_amdgcn_mfma_f32_16x16x32_bf16(a, b1, acc[br][1], 0, 0, 0);
            }
        }
    }

    #pragma unroll
    for (int br = 0; br < 3; ++br) {
        float* outp = KXpart3 + (((size_t)br * NCHUNK_ + nc) * B_ + b) * M_ * C_;
        #pragma unroll
        for (int r = 0; r < 4; ++r) {
            int m = w * 16 + lkg * 4 + r;
            outp[(size_t)m * C_ + c0 + lrow]      = acc[br][0][r];
            outp[(size_t)m * C_ + c0 + 16 + lrow] = acc[br][1][r];
        }
    }
}

// ---------------------------------------------------------------------------
// Kernel 3b: reduce partials for all branches (fixed order — deterministic).
// ---------------------------------------------------------------------------
__global__ __launch_bounds__(256) void kx3_reduce(const float* __restrict__ KXpart3,
                                                  float* __restrict__ KX)
{
    const size_t BMC = (size_t)B_ * M_ * C_;
    size_t i = (size_t)blockIdx.x * 256 + threadIdx.x;
    if (i >= 3 * BMC) return;
    int br = (int)(i / BMC);
    size_t rem = i - (size_t)br * BMC;
    float s = 0.f;
    #pragma unroll
    for (int nc = 0; nc < NCHUNK_; ++nc)
        s += KXpart3[((size_t)br * NCHUNK_ + nc) * BMC + rem];
    size_t b = rem / ((size_t)M_ * C_);
    size_t mc = rem - b * (size_t)M_ * C_;
    KX[((size_t)b * 3 + br) * M_ * C_ + mc] = s;
}

// ---------------------------------------------------------------------------
// Kernel 4a (MFMA): WlWvPart[pc][c][k] = sum_{p in chunk pc} Wl[c][p]*Wv[p][k]
// ---------------------------------------------------------------------------
__global__ __launch_bounds__(256) void wlwv_mfma(const float* __restrict__ Wl,
                                                 const float* __restrict__ Wv,
                                                 float* __restrict__ part)
{
    const int k0 = blockIdx.x * 64;
    const int c0 = blockIdx.y * 64;
    const int pc = blockIdx.z;

    __shared__ short Al[64][72];
    __shared__ short Bt[64][72];

    const int tid  = threadIdx.x;
    const int lane = tid & 63;
    const int w    = tid >> 6;
    const int lrow = lane & 15;
    const int lkg  = lane >> 4;
    const int pq = tid >> 4;
    const int nq = tid & 15;

    f32x4 acc[4] = {{0.f,0.f,0.f,0.f},{0.f,0.f,0.f,0.f},{0.f,0.f,0.f,0.f},{0.f,0.f,0.f,0.f}};

    for (int it = 0; it < 2; ++it) {
        const int p0 = pc * 128 + it * 64;
        __syncthreads();
        #pragma unroll
        for (int i = 0; i < 4; ++i) {
            int f = tid + i * 256;
            int r = f >> 4, c4 = (f & 15) * 4;
            f32x4 v = *reinterpret_cast<const f32x4*>(&Wl[(size_t)(c0 + r) * C_ + p0 + c4]);
            short4 s;
            s.x = f2bf(v[0]); s.y = f2bf(v[1]); s.z = f2bf(v[2]); s.w = f2bf(v[3]);
            *reinterpret_cast<short4*>(&Al[r][c4]) = s;
        }
        f32x4 v0 = *reinterpret_cast<const f32x4*>(&Wv[(size_t)(p0 + pq * 4 + 0) * C_ + k0 + nq * 4]);
        f32x4 v1 = *reinterpret_cast<const f32x4*>(&Wv[(size_t)(p0 + pq * 4 + 1) * C_ + k0 + nq * 4]);
        f32x4 v2 = *reinterpret_cast<const f32x4*>(&Wv[(size_t)(p0 + pq * 4 + 2) * C_ + k0 + nq * 4]);
        f32x4 v3 = *reinterpret_cast<const f32x4*>(&Wv[(size_t)(p0 + pq * 4 + 3) * C_ + k0 + nq * 4]);
        #pragma unroll
        for (int c = 0; c < 4; ++c) {
            short4 s;
            s.x = f2bf(v0[c]); s.y = f2bf(v1[c]); s.z = f2bf(v2[c]); s.w = f2bf(v3[c]);
            *reinterpret_cast<short4*>(&Bt[nq * 4 + c][pq * 4]) = s;
        }
        __syncthreads();
        #pragma unroll
        for (int ks = 0; ks < 2; ++ks) {
            bf16x8 a = *reinterpret_cast<const bf16x8*>(&Al[w * 16 + lrow][ks * 32 + lkg * 8]);
            #pragma unroll
            for (int ns = 0; ns < 4; ++ns) {
                bf16x8 bx = *reinterpret_cast<const bf16x8*>(&Bt[ns * 16 + lrow][ks * 32 + lkg * 8]);
                acc[ns] = __builtin_amdgcn_mfma_f32_16x16x32_bf16(a, bx, acc[ns], 0, 0, 0);
            }
        }
    }

    float* pp = part + (size_t)pc * C_ * C_;
    #pragma unroll
    for (int r = 0; r < 4; ++r) {
        int c = c0 + w * 16 + lkg * 4 + r;
        #pragma unroll
        for (int ns = 0; ns < 4; ++ns) {
            int k = k0 + ns * 16 + lrow;
            pp[(size_t)c * C_ + k] = acc[ns][r];
        }
    }
}

// Kernel 4b: WlWv[i] = sum_pc part[pc][i]  (fixed order)
__global__ __launch_bounds__(256) void wlwv_reduce(const float* __restrict__ part,
                                                   float* __restrict__ WlWv)
{
    const size_t CC = (size_t)C_ * C_;
    size_t i = (size_t)blockIdx.x * 256 + threadIdx.x;
    if (i >= CC) return;
    float s = 0.f;
    #pragma unroll
    for (int pc = 0; pc < 4; ++pc) s += part[pc * CC + i];
    WlWv[i] = s;
}

// Wlbv[c] = sum_p Wl[c][p] * bv[p]
__global__ __launch_bounds__(256) void wlbv_kernel(const float* __restrict__ Wl,
                                                   const float* __restrict__ bv,
                                                   float* __restrict__ Wlbv)
{
    int c = blockIdx.x * 256 + threadIdx.x;
    if (c < C_) {
        float s = 0.f;
        for (int p = 0; p < C_; ++p) s = fmaf(Wl[(size_t)c * C_ + p], bv[p], s);
        Wlbv[c] = s;
    }
}

// ---------------------------------------------------------------------------
// Kernel 5 (MFMA): Wf[b][br][c][m] = sum_k WlWv[c][k]*KX[b][br][m][k]
//                                    + Ksum[b][br][m]*Wlbv[c]
// ---------------------------------------------------------------------------
__global__ __launch_bounds__(256) void wfused_mfma(const float* __restrict__ WlWv,
                                                   const float* __restrict__ KX,
                                                   const float* __restrict__ Ksum,
                                                   const float* __restrict__ Wlbv,
                                                   float* __restrict__ Wf)
{
    const int c0 = blockIdx.x * 64;
    const int br = blockIdx.y;
    const int b  = blockIdx.z;

    __shared__ short Al[64][72];   // WlWv[c][k] bf16
    __shared__ short Bl[64][72];   // KX[m][k] bf16

    const int tid  = threadIdx.x;
    const int lane = tid & 63;
    const int w    = tid >> 6;
    const int lrow = lane & 15;
    const int lkg  = lane >> 4;

    const float* kxb = KX + ((size_t)b * 3 + br) * M_ * C_;

    f32x4 acc[4] = {{0.f,0.f,0.f,0.f},{0.f,0.f,0.f,0.f},{0.f,0.f,0.f,0.f},{0.f,0.f,0.f,0.f}};

    for (int kc = 0; kc < C_ / 64; ++kc) {
        const int k0 = kc * 64;
        __syncthreads();
        #pragma unroll
        for (int i = 0; i < 4; ++i) {
            int f = tid + i * 256;
            int r = f >> 4, c4 = (f & 15) * 4;
            f32x4 v = *reinterpret_cast<const f32x4*>(&WlWv[(size_t)(c0 + r) * C_ + k0 + c4]);
            short4 s;
            s.x = f2bf(v[0]); s.y = f2bf(v[1]); s.z = f2bf(v[2]); s.w = f2bf(v[3]);
            *reinterpret_cast<short4*>(&Al[r][c4]) = s;
        }
        #pragma unroll
        for (int i = 0; i < 4; ++i) {
            int f = tid + i * 256;
            int r = f >> 4, c4 = (f & 15) * 4;
            f32x4 v = *reinterpret_cast<const f32x4*>(&kxb[(size_t)r * C_ + k0 + c4]);
            short4 s;
            s.x = f2bf(v[0]); s.y = f2bf(v[1]); s.z = f2bf(v[2]); s.w = f2bf(v[3]);
            *reinterpret_cast<short4*>(&Bl[r][c4]) = s;
        }
        __syncthreads();
        #pragma unroll
        for (int ks = 0; ks < 2; ++ks) {
            bf16x8 a = *reinterpret_cast<const bf16x8*>(&Al[w * 16 + lrow][ks * 32 + lkg * 8]);
            #pragma unroll
            for (int ns = 0; ns < 4; ++ns) {
                bf16x8 bx = *reinterpret_cast<const bf16x8*>(&Bl[ns * 16 + lrow][ks * 32 + lkg * 8]);
                acc[ns] = __builtin_amdgcn_mfma_f32_16x16x32_bf16(a, bx, acc[ns], 0, 0, 0);
            }
        }
    }

    const float* ks_ = Ksum + ((size_t)b * 3 + br) * M_;
    float* wfb = Wf + (((size_t)b * 3 + br) * C_) * M_;
    #pragma unroll
    for (int r = 0; r < 4; ++r) {
        int c = c0 + w * 16 + lkg * 4 + r;
        float wb = Wlbv[c];
        #pragma unroll
        for (int ns = 0; ns < 4; ++ns) {
            int m = ns * 16 + lrow;
            wfb[(size_t)c * M_ + m] = acc[ns][r] + ks_[m] * wb;
        }
    }
}

// ---------------------------------------------------------------------------
// Kernel 6 (MFMA): out = x + gamma*(bl + sum_br norm_br * (Wf_br @ QT^T)).
// ---------------------------------------------------------------------------
__global__ __launch_bounds__(256) void final_mfma_kernel(
    const short* __restrict__ QT, const float* __restrict__ Wf,
    const float* __restrict__ Ksum, const float* __restrict__ x,
    const float* __restrict__ bl, const float* __restrict__ gamma,
    float* __restrict__ out)
{
    const int n0 = blockIdx.x * 64;
    const int c0 = blockIdx.y * 64;
    const int b  = blockIdx.z;

    __shared__ short Qs[64][72];      // [n][m] bf16
    __shared__ short Wfs[3][64][72];  // [br][c][m] bf16
    __shared__ float norms[3][64];
    __shared__ float ksef[3][64];

    const int tid  = threadIdx.x;
    const int lane = tid & 63;
    const int w    = tid >> 6;
    const int lrow = lane & 15;
    const int lkg  = lane >> 4;

    const short* qtb = QT + (size_t)b * N_ * M_;
    #pragma unroll
    for (int i = 0; i < 2; ++i) {
        int f = tid + i * 256;
        int r = f >> 3, m8 = (f & 7) * 8;
        *reinterpret_cast<int4*>(&Qs[r][m8]) =
            *reinterpret_cast<const int4*>(&qtb[(size_t)(n0 + r) * M_ + m8]);
    }
    #pragma unroll
    for (int br = 0; br < 3; ++br) {
        const float* wfb = Wf + (((size_t)b * 3 + br) * C_ + c0) * M_;
        #pragma unroll
        for (int i = 0; i < 4; ++i) {
            int f = tid + i * 256;
            int r = f >> 4, m4 = (f & 15) * 4;
            float4 v = *reinterpret_cast<const float4*>(&wfb[(size_t)r * M_ + m4]);
            short4 s;
            s.x = f2bf(v.x); s.y = f2bf(v.y); s.z = f2bf(v.z); s.w = f2bf(v.w);
            *reinterpret_cast<short4*>(&Wfs[br][r][m4]) = s;
        }
    }
    if (tid < 192) {
        int br = tid >> 6, m = tid & 63;
        ksef[br][m] = Ksum[((size_t)b * 3 + br) * M_ + m] + EPS_;
    }
    __syncthreads();
    if (tid < 192) {
        int br = tid >> 6, n = tid & 63;
        float s = 0.f;
        #pragma unroll 16
        for (int m = 0; m < 64; ++m) s = fmaf(bf2f(Qs[n][m]), ksef[br][m], s);
        norms[br][n] = 1.0f / s;
    }
    __syncthreads();

    f32x4 tot[4] = {{0.f,0.f,0.f,0.f},{0.f,0.f,0.f,0.f},{0.f,0.f,0.f,0.f},{0.f,0.f,0.f,0.f}};
    for (int br = 0; br < 3; ++br) {
        f32x4 acc[4] = {{0.f,0.f,0.f,0.f},{0.f,0.f,0.f,0.f},{0.f,0.f,0.f,0.f},{0.f,0.f,0.f,0.f}};
        #pragma unroll
        for (int ks = 0; ks < 2; ++ks) {
            bf16x8 a = *reinterpret_cast<const bf16x8*>(&Wfs[br][w * 16 + lrow][ks * 32 + lkg * 8]);
            #pragma unroll
            for (int ns = 0; ns < 4; ++ns) {
                bf16x8 bq = *reinterpret_cast<const bf16x8*>(&Qs[ns * 16 + lrow][ks * 32 + lkg * 8]);
                acc[ns] = __builtin_amdgcn_mfma_f32_16x16x32_bf16(a, bq, acc[ns], 0, 0, 0);
            }
        }
        #pragma unroll
        for (int ns = 0; ns < 4; ++ns) {
            float nf = norms[br][ns * 16 + lrow];
            #pragma unroll
            for (int r = 0; r < 4; ++r) tot[ns][r] = fmaf(nf, acc[ns][r], tot[ns][r]);
        }
    }

    const float g = gamma[0];
    const float* xb = x + (size_t)b * C_ * N_;
    float* ob = out + (size_t)b * C_ * N_;
    #pragma unroll
    for (int r = 0; r < 4; ++r) {
        int c = c0 + w * 16 + lkg * 4 + r;
        float blc = bl[c];
        #pragma unroll
        for (int ns = 0; ns < 4; ++ns) {
            int n = n0 + ns * 16 + lrow;
            ob[(size_t)c * N_ + n] = fmaf(g, tot[ns][r] + blc, xb[(size_t)c * N_ + n]);
        }
    }
}

// ---------------------------------------------------------------------------
extern "C" void kernel_launch(void* const* d_in, const int* in_sizes, int n_in,
                              void* d_out, int out_size, void* d_ws, size_t ws_size,
                              hipStream_t stream)
{
    const float* x   = (const float*)d_in[0];
    const float* y   = (const float*)d_in[1];
    const float* z   = (const float*)d_in[2];
    const float* Wq  = (const float*)d_in[3];
    const float* bq  = (const float*)d_in[4];
    const float* Wk1 = (const float*)d_in[5];
    const float* bk1 = (const float*)d_in[6];
    const float* Wk2 = (const float*)d_in[7];
    const float* bk2 = (const float*)d_in[8];
    const float* Wk3 = (const float*)d_in[9];
    const float* bk3 = (const float*)d_in[10];
    const float* Wv  = (const float*)d_in[11];
    const float* bv  = (const float*)d_in[12];
    const float* Wl  = (const float*)d_in[13];
    const float* bl  = (const float*)d_in[14];
    const float* gamma = (const float*)d_in[15];
    float* out = (float*)d_out;

    // workspace layout (~35 MB of the 256 MiB d_ws).
    float* ws = (float*)d_ws;
    const size_t QSZ  = (size_t)B_ * M_ * N_;        // 2,097,152 elements
    const size_t BMC  = (size_t)B_ * M_ * C_;        //   262,144
    short* QTs   = (short*)ws;                        // [B][N][M] bf16
    short* Kbuf3 = QTs + QSZ;                         // [3][B][M][N] bf16 (12 MB)
    float* fbase = ws + 2 * QSZ;                      // float region
    float* KX    = fbase;                             // [B][3][M][C]
    float* Ksum  = KX + 3 * BMC;                      // [B][3][M]
    float* WlWv  = Ksum + (size_t)B_ * 3 * M_;        // [C][C]
    float* Wlbv  = WlWv + (size_t)C_ * C_;            // [C]
    float* Ksumpart = Wlbv + C_;                      // [3][B][64][M]
    float* KXpart3  = Ksumpart + (size_t)3 * B_ * 64 * M_;  // [3][4][B][M][C] (12MB)
    float* WlWvPart = KXpart3;                        // alias (4MB, dead before wlwv)
    float* Wf   = KXpart3;                            // alias (3MB, after kx3_reduce)
    short* Wbf  = (short*)(KXpart3 + (size_t)3 * NCHUNK_ * BMC);  // [4][M][C] bf16

    dim3 blk(256);

    // 0) one-time bf16 conversion of the 4 feature weight matrices
    prep_w<<<dim3((M_ * C_ + 255) / 256), blk, 0, stream>>>(Wq, Wk1, Wk2, Wk3, Wbf);
    // 1) feature GEMMs: y=0 computes Q+K1 off one x staging; y=1,2 -> K2,K3
    feat_mfma<<<dim3(N_ / 64, 3, B_), blk, 0, stream>>>(
        x, y, z, Wbf, bq, bk1, bk2, bk3, QTs, Kbuf3, Ksumpart);
    // 2) finalize ksum for all branches
    ksum_finalize<<<dim3((3 * B_ * M_ + 255) / 256), blk, 0, stream>>>(Ksumpart, Ksum);
    // 3) KX for all branches in one pass (x staged once per tile)
    kx3_mfma<<<dim3(C_ / 32, NCHUNK_, B_), blk, 0, stream>>>(Kbuf3, x, KXpart3);
    kx3_reduce<<<dim3((int)((3 * BMC + 255) / 256)), blk, 0, stream>>>(KXpart3, KX);

    // 4) batch-independent fused weights (partials alias KXpart3 — after kx3_reduce)
    wlwv_mfma<<<dim3(C_ / 64, C_ / 64, 4), blk, 0, stream>>>(Wl, Wv, WlWvPart);
    wlwv_reduce<<<dim3(((int)((size_t)C_ * C_) + 255) / 256), blk, 0, stream>>>(WlWvPart, WlWv);
    wlbv_kernel<<<dim3((C_ + 255) / 256), blk, 0, stream>>>(Wl, bv, Wlbv);
    // 5) per-batch fused weights
    wfused_mfma<<<dim3(C_ / 64, 3, B_), blk, 0, stream>>>(WlWv, KX, Ksum, Wlbv, Wf);
    // 6) final: norms + MFMA GEMM + bias + residual
    final_mfma_kernel<<<dim3(N_ / 64, C_ / 64, B_), blk, 0, stream>>>(
        QTs, Wf, Ksum, x, bl, gamma, out);
}

// Round 20
// 165.440 us; speedup vs baseline: 1.2416x; 1.2416x over previous
//
#include <hip/hip_runtime.h>
#include <hip/hip_bf16.h>
#include <math.h>

// Problem constants
constexpr int B_ = 8;
constexpr int C_ = 512;
constexpr int M_ = 64;     // C/8
constexpr int N_ = 4096;   // H*W
constexpr int NCHUNK_ = 4; // split-N factor for kx
constexpr float EPS_ = 1e-10f;
constexpr float PARAM_ = 10.0f;

typedef __attribute__((ext_vector_type(4))) float f32x4;
typedef __attribute__((ext_vector_type(8))) short bf16x8;   // 8 bf16 in 4 VGPRs

// elus feature map: t>0 ? 10t+1 : exp(10t)
__device__ __forceinline__ float elus(float t) {
    return (t > 0.f) ? fmaf(PARAM_, t, 1.f) : expf(PARAM_ * t);
}

// fp32 -> bf16 RTNE via the intrinsic the compiler can pack into
// v_cvt_pk_bf16_f32 (hand-rolled bit-twiddle defeated that fusion).
__device__ __forceinline__ short f2bf(float f) {
    return __builtin_bit_cast(short, __float2bfloat16(f));
}
// bf16 bits -> fp32
__device__ __forceinline__ float bf2f(short s) {
    unsigned u = ((unsigned)(unsigned short)s) << 16;
    return __builtin_bit_cast(float, u);
}

// ---------------------------------------------------------------------------
// Kernel 0: convert the 4 feature weight matrices to bf16 once.
// Wbf layout: [4][M][C]  (0=Wq, 1=Wk1, 2=Wk2, 3=Wk3)
// ---------------------------------------------------------------------------
__global__ __launch_bounds__(256) void prep_w(const float* __restrict__ Wq,
                                              const float* __restrict__ Wk1,
                                              const float* __restrict__ Wk2,
                                              const float* __restrict__ Wk3,
                                              short* __restrict__ Wbf)
{
    int i = blockIdx.x * 256 + threadIdx.x;
    const int MC = M_ * C_;
    if (i < MC) {
        Wbf[i]          = f2bf(Wq[i]);
        Wbf[MC + i]     = f2bf(Wk1[i]);
        Wbf[2 * MC + i] = f2bf(Wk2[i]);
        Wbf[3 * MC + i] = f2bf(Wk3[i]);
    }
}

// ---------------------------------------------------------------------------
// Kernel 1 (MFMA): feature GEMMs.
// blockIdx.y = 0: x branch — computes BOTH Q (QT output) and K1 (x staged once,
//                 two W tiles, 2x MFMA).
// blockIdx.y = 1: y -> K2.   blockIdx.y = 2: z -> K3.
// W is pre-converted bf16 (raw int4 LDS copies, no per-block conversion).
// NOTE (R18 post-mortem): register-prefetch software pipelining (T14) was
// tried and REGRESSED (VGPR 56->92, occupancy 32->19%, total +40us) — the
// plain barriered loop below is the verified-best form.
// ---------------------------------------------------------------------------
__global__ __launch_bounds__(256) void feat_mfma(
    const float* __restrict__ x, const float* __restrict__ y,
    const float* __restrict__ z, const short* __restrict__ Wbf,
    const float* __restrict__ bq, const float* __restrict__ bk1,
    const float* __restrict__ bk2, const float* __restrict__ bk3,
    short* __restrict__ QT, short* __restrict__ Kbuf3,
    float* __restrict__ Ksumpart)
{
    const int n0 = blockIdx.x * 64;
    const int which = blockIdx.y;       // 0:x->(Q,K1)  1:y->K2  2:z->K3
    const int b  = blockIdx.z;
    const int MC = M_ * C_;

    const float* in = (which == 0) ? x : (which == 1) ? y : z;
    const short* Ws0 = Wbf + (size_t)((which == 0) ? 0 : which + 1) * MC;
    const short* Ws1 = Wbf + (size_t)MC;   // Wk1 (fused path only)

    __shared__ short Wlds[2][64][72];
    __shared__ short Xlds[64][72];

    const int tid  = threadIdx.x;
    const int lane = tid & 63;
    const int w    = tid >> 6;
    const int lrow = lane & 15;
    const int lkg  = lane >> 4;

    const float* inb = in + (size_t)b * C_ * N_;

    f32x4 accA[4] = {{0.f,0.f,0.f,0.f},{0.f,0.f,0.f,0.f},{0.f,0.f,0.f,0.f},{0.f,0.f,0.f,0.f}};
    f32x4 accB[4] = {{0.f,0.f,0.f,0.f},{0.f,0.f,0.f,0.f},{0.f,0.f,0.f,0.f},{0.f,0.f,0.f,0.f}};

    const int kq = tid >> 4;   // 0..15 -> k base kq*4 (X transpose staging)
    const int nq = tid & 15;   // 0..15 -> n base nq*4

    for (int kc = 0; kc < C_ / 64; ++kc) {
        const int k0 = kc * 64;
        __syncthreads();   // previous chunk's frag reads done
        // stage W tile(s): bf16 source, raw int4 copies (0-conflict pattern)
        #pragma unroll
        for (int i = 0; i < 2; ++i) {
            int f = tid + i * 256;
            int r = f >> 3, c8 = (f & 7) * 8;
            *reinterpret_cast<int4*>(&Wlds[0][r][c8]) =
                *reinterpret_cast<const int4*>(&Ws0[(size_t)r * C_ + k0 + c8]);
        }
        if (which == 0) {
            #pragma unroll
            for (int i = 0; i < 2; ++i) {
                int f = tid + i * 256;
                int r = f >> 3, c8 = (f & 7) * 8;
                *reinterpret_cast<int4*>(&Wlds[1][r][c8]) =
                    *reinterpret_cast<const int4*>(&Ws1[(size_t)r * C_ + k0 + c8]);
            }
        }
        // stage X tile transposed (4x4 in-register transpose, fp32 -> bf16)
        f32x4 v0 = *reinterpret_cast<const f32x4*>(&inb[(size_t)(k0 + kq * 4 + 0) * N_ + n0 + nq * 4]);
        f32x4 v1 = *reinterpret_cast<const f32x4*>(&inb[(size_t)(k0 + kq * 4 + 1) * N_ + n0 + nq * 4]);
        f32x4 v2 = *reinterpret_cast<const f32x4*>(&inb[(size_t)(k0 + kq * 4 + 2) * N_ + n0 + nq * 4]);
        f32x4 v3 = *reinterpret_cast<const f32x4*>(&inb[(size_t)(k0 + kq * 4 + 3) * N_ + n0 + nq * 4]);
        #pragma unroll
        for (int c = 0; c < 4; ++c) {
            short4 s;
            s.x = f2bf(v0[c]); s.y = f2bf(v1[c]); s.z = f2bf(v2[c]); s.w = f2bf(v3[c]);
            *reinterpret_cast<short4*>(&Xlds[nq * 4 + c][kq * 4]) = s;
        }
        __syncthreads();
        #pragma unroll
        for (int ks = 0; ks < 2; ++ks) {
            bf16x8 a0 = *reinterpret_cast<const bf16x8*>(&Wlds[0][w * 16 + lrow][ks * 32 + lkg * 8]);
            bf16x8 a1;
            if (which == 0)
                a1 = *reinterpret_cast<const bf16x8*>(&Wlds[1][w * 16 + lrow][ks * 32 + lkg * 8]);
            #pragma unroll
            for (int ns = 0; ns < 4; ++ns) {
                bf16x8 bx = *reinterpret_cast<const bf16x8*>(&Xlds[ns * 16 + lrow][ks * 32 + lkg * 8]);
                accA[ns] = __builtin_amdgcn_mfma_f32_16x16x32_bf16(a0, bx, accA[ns], 0, 0, 0);
                if (which == 0)
                    accB[ns] = __builtin_amdgcn_mfma_f32_16x16x32_bf16(a1, bx, accB[ns], 0, 0, 0);
            }
        }
    }

    // --- epilogues ---
    // K-branch writer (Kbuf3[br] bf16 + ksum partials via 16-lane shfl reduce)
    auto writeK = [&](const f32x4* acc, const float* bias, int br) {
        short* outb = Kbuf3 + ((size_t)br * B_ + b) * M_ * N_;
        float* ksp  = Ksumpart + ((size_t)br * B_ + b) * 64 * M_;  // [nblk][m]
        #pragma unroll
        for (int r = 0; r < 4; ++r) {
            int m = w * 16 + lkg * 4 + r;
            float bi = bias[m];
            float sv = 0.f;
            #pragma unroll
            for (int ns = 0; ns < 4; ++ns) {
                int n = n0 + ns * 16 + lrow;
                float e = elus(acc[ns][r] + bi);
                outb[(size_t)m * N_ + n] = f2bf(e);
                sv += e;
            }
            sv += __shfl_xor(sv, 1);
            sv += __shfl_xor(sv, 2);
            sv += __shfl_xor(sv, 4);
            sv += __shfl_xor(sv, 8);
            if (lrow == 0)
                ksp[(size_t)blockIdx.x * M_ + m] = sv;
        }
    };

    if (which == 0) {
        // Q from accA -> QT[b][n][m] bf16 (short4 along m)
        short* outb = QT + (size_t)b * N_ * M_;
        int mbase = w * 16 + lkg * 4;
        float bi[4];
        #pragma unroll
        for (int r = 0; r < 4; ++r) bi[r] = bq[mbase + r];
        #pragma unroll
        for (int ns = 0; ns < 4; ++ns) {
            int n = n0 + ns * 16 + lrow;
            short4 s;
            s.x = f2bf(elus(accA[ns][0] + bi[0]));
            s.y = f2bf(elus(accA[ns][1] + bi[1]));
            s.z = f2bf(elus(accA[ns][2] + bi[2]));
            s.w = f2bf(elus(accA[ns][3] + bi[3]));
            *reinterpret_cast<short4*>(&outb[(size_t)n * M_ + mbase]) = s;
        }
        // K1 from accB
        writeK(accB, bk1, 0);
    } else {
        writeK(accA, (which == 1) ? bk2 : bk3, which);
    }
}

// ---------------------------------------------------------------------------
// Kernel 2: Ksum[b][br][m] = sum_nb Ksumpart[br][b][nb][m]  (all branches)
// ---------------------------------------------------------------------------
__global__ __launch_bounds__(256) void ksum_finalize(const float* __restrict__ Ksumpart,
                                                     float* __restrict__ Ksum)
{
    int i = blockIdx.x * 256 + threadIdx.x;   // (br, b, m)
    if (i >= 3 * B_ * M_) return;
    int br = i / (B_ * M_);
    int rem = i - br * (B_ * M_);
    int b = rem >> 6, m = rem & 63;
    const float* ksp = Ksumpart + ((size_t)br * B_ + b) * 64 * M_;
    float s = 0.f;
    #pragma unroll 8
    for (int nb = 0; nb < 64; ++nb) s += ksp[(size_t)nb * M_ + m];
    Ksum[((size_t)b * 3 + br) * M_ + m] = s;
}

// ---------------------------------------------------------------------------
// Kernel 3a (MFMA): split-N partial KX for ALL THREE branches in one pass.
// ---------------------------------------------------------------------------
__global__ __launch_bounds__(256) void kx3_mfma(const short* __restrict__ Kbuf3,
                                                const float* __restrict__ x,
                                                float* __restrict__ KXpart3)
{
    const int c0 = blockIdx.x * 32;
    const int nc = blockIdx.y;
    const int b  = blockIdx.z;
    const int nbeg = nc * (N_ / NCHUNK_);

    __shared__ short Klds[3][64][72];
    __shared__ short Xlds[32][72];

    const int tid  = threadIdx.x;
    const int lane = tid & 63;
    const int w    = tid >> 6;
    const int lrow = lane & 15;
    const int lkg  = lane >> 4;

    const float* xb = x + ((size_t)b * C_ + c0) * N_;

    f32x4 acc[3][2] = {};

    for (int it = 0; it < (N_ / NCHUNK_) / 64; ++it) {
        const int n0 = nbeg + it * 64;
        __syncthreads();
        #pragma unroll
        for (int br = 0; br < 3; ++br) {
            const short* kb = Kbuf3 + ((size_t)br * B_ + b) * M_ * N_;
            #pragma unroll
            for (int i = 0; i < 2; ++i) {
                int f = tid + i * 256;
                int r = f >> 3, c8 = (f & 7) * 8;
                *reinterpret_cast<int4*>(&Klds[br][r][c8]) =
                    *reinterpret_cast<const int4*>(&kb[(size_t)r * N_ + n0 + c8]);
            }
        }
        #pragma unroll
        for (int i = 0; i < 2; ++i) {
            int f = tid + i * 256;
            int r = f >> 4, c4 = (f & 15) * 4;
            float4 v = *reinterpret_cast<const float4*>(&xb[(size_t)r * N_ + n0 + c4]);
            short4 s;
            s.x = f2bf(v.x); s.y = f2bf(v.y); s.z = f2bf(v.z); s.w = f2bf(v.w);
            *reinterpret_cast<short4*>(&Xlds[r][c4]) = s;
        }
        __syncthreads();
        #pragma unroll
        for (int s = 0; s < 2; ++s) {
            bf16x8 b0 = *reinterpret_cast<const bf16x8*>(&Xlds[lrow][s * 32 + lkg * 8]);
            bf16x8 b1 = *reinterpret_cast<const bf16x8*>(&Xlds[16 + lrow][s * 32 + lkg * 8]);
            #pragma unroll
            for (int br = 0; br < 3; ++br) {
                bf16x8 a = *reinterpret_cast<const bf16x8*>(&Klds[br][w * 16 + lrow][s * 32 + lkg * 8]);
                acc[br][0] = __builtin_amdgcn_mfma_f32_16x16x32_bf16(a, b0, acc[br][0], 0, 0, 0);
                acc[br][1] = __builtin_amdgcn_mfma_f32_16x16x32_bf16(a, b1, acc[br][1], 0, 0, 0);
            }
        }
    }

    #pragma unroll
    for (int br = 0; br < 3; ++br) {
        float* outp = KXpart3 + (((size_t)br * NCHUNK_ + nc) * B_ + b) * M_ * C_;
        #pragma unroll
        for (int r = 0; r < 4; ++r) {
            int m = w * 16 + lkg * 4 + r;
            outp[(size_t)m * C_ + c0 + lrow]      = acc[br][0][r];
            outp[(size_t)m * C_ + c0 + 16 + lrow] = acc[br][1][r];
        }
    }
}

// ---------------------------------------------------------------------------
// Kernel 3b: reduce partials for all branches (fixed order — deterministic).
// ---------------------------------------------------------------------------
__global__ __launch_bounds__(256) void kx3_reduce(const float* __restrict__ KXpart3,
                                                  float* __restrict__ KX)
{
    const size_t BMC = (size_t)B_ * M_ * C_;
    size_t i = (size_t)blockIdx.x * 256 + threadIdx.x;
    if (i >= 3 * BMC) return;
    int br = (int)(i / BMC);
    size_t rem = i - (size_t)br * BMC;
    float s = 0.f;
    #pragma unroll
    for (int nc = 0; nc < NCHUNK_; ++nc)
        s += KXpart3[((size_t)br * NCHUNK_ + nc) * BMC + rem];
    size_t b = rem / ((size_t)M_ * C_);
    size_t mc = rem - b * (size_t)M_ * C_;
    KX[((size_t)b * 3 + br) * M_ * C_ + mc] = s;
}

// ---------------------------------------------------------------------------
// Kernel 4a (MFMA): WlWvPart[pc][c][k] = sum_{p in chunk pc} Wl[c][p]*Wv[p][k]
// ---------------------------------------------------------------------------
__global__ __launch_bounds__(256) void wlwv_mfma(const float* __restrict__ Wl,
                                                 const float* __restrict__ Wv,
                                                 float* __restrict__ part)
{
    const int k0 = blockIdx.x * 64;
    const int c0 = blockIdx.y * 64;
    const int pc = blockIdx.z;

    __shared__ short Al[64][72];
    __shared__ short Bt[64][72];

    const int tid  = threadIdx.x;
    const int lane = tid & 63;
    const int w    = tid >> 6;
    const int lrow = lane & 15;
    const int lkg  = lane >> 4;
    const int pq = tid >> 4;
    const int nq = tid & 15;

    f32x4 acc[4] = {{0.f,0.f,0.f,0.f},{0.f,0.f,0.f,0.f},{0.f,0.f,0.f,0.f},{0.f,0.f,0.f,0.f}};

    for (int it = 0; it < 2; ++it) {
        const int p0 = pc * 128 + it * 64;
        __syncthreads();
        #pragma unroll
        for (int i = 0; i < 4; ++i) {
            int f = tid + i * 256;
            int r = f >> 4, c4 = (f & 15) * 4;
            f32x4 v = *reinterpret_cast<const f32x4*>(&Wl[(size_t)(c0 + r) * C_ + p0 + c4]);
            short4 s;
            s.x = f2bf(v[0]); s.y = f2bf(v[1]); s.z = f2bf(v[2]); s.w = f2bf(v[3]);
            *reinterpret_cast<short4*>(&Al[r][c4]) = s;
        }
        f32x4 v0 = *reinterpret_cast<const f32x4*>(&Wv[(size_t)(p0 + pq * 4 + 0) * C_ + k0 + nq * 4]);
        f32x4 v1 = *reinterpret_cast<const f32x4*>(&Wv[(size_t)(p0 + pq * 4 + 1) * C_ + k0 + nq * 4]);
        f32x4 v2 = *reinterpret_cast<const f32x4*>(&Wv[(size_t)(p0 + pq * 4 + 2) * C_ + k0 + nq * 4]);
        f32x4 v3 = *reinterpret_cast<const f32x4*>(&Wv[(size_t)(p0 + pq * 4 + 3) * C_ + k0 + nq * 4]);
        #pragma unroll
        for (int c = 0; c < 4; ++c) {
            short4 s;
            s.x = f2bf(v0[c]); s.y = f2bf(v1[c]); s.z = f2bf(v2[c]); s.w = f2bf(v3[c]);
            *reinterpret_cast<short4*>(&Bt[nq * 4 + c][pq * 4]) = s;
        }
        __syncthreads();
        #pragma unroll
        for (int ks = 0; ks < 2; ++ks) {
            bf16x8 a = *reinterpret_cast<const bf16x8*>(&Al[w * 16 + lrow][ks * 32 + lkg * 8]);
            #pragma unroll
            for (int ns = 0; ns < 4; ++ns) {
                bf16x8 bx = *reinterpret_cast<const bf16x8*>(&Bt[ns * 16 + lrow][ks * 32 + lkg * 8]);
                acc[ns] = __builtin_amdgcn_mfma_f32_16x16x32_bf16(a, bx, acc[ns], 0, 0, 0);
            }
        }
    }

    float* pp = part + (size_t)pc * C_ * C_;
    #pragma unroll
    for (int r = 0; r < 4; ++r) {
        int c = c0 + w * 16 + lkg * 4 + r;
        #pragma unroll
        for (int ns = 0; ns < 4; ++ns) {
            int k = k0 + ns * 16 + lrow;
            pp[(size_t)c * C_ + k] = acc[ns][r];
        }
    }
}

// Kernel 4b: WlWv[i] = sum_pc part[pc][i]  (fixed order)
__global__ __launch_bounds__(256) void wlwv_reduce(const float* __restrict__ part,
                                                   float* __restrict__ WlWv)
{
    const size_t CC = (size_t)C_ * C_;
    size_t i = (size_t)blockIdx.x * 256 + threadIdx.x;
    if (i >= CC) return;
    float s = 0.f;
    #pragma unroll
    for (int pc = 0; pc < 4; ++pc) s += part[pc * CC + i];
    WlWv[i] = s;
}

// Wlbv[c] = sum_p Wl[c][p] * bv[p]
__global__ __launch_bounds__(256) void wlbv_kernel(const float* __restrict__ Wl,
                                                   const float* __restrict__ bv,
                                                   float* __restrict__ Wlbv)
{
    int c = blockIdx.x * 256 + threadIdx.x;
    if (c < C_) {
        float s = 0.f;
        for (int p = 0; p < C_; ++p) s = fmaf(Wl[(size_t)c * C_ + p], bv[p], s);
        Wlbv[c] = s;
    }
}

// ---------------------------------------------------------------------------
// Kernel 5 (MFMA): Wf[b][br][c][m] = sum_k WlWv[c][k]*KX[b][br][m][k]
//                                    + Ksum[b][br][m]*Wlbv[c]
// ---------------------------------------------------------------------------
__global__ __launch_bounds__(256) void wfused_mfma(const float* __restrict__ WlWv,
                                                   const float* __restrict__ KX,
                                                   const float* __restrict__ Ksum,
                                                   const float* __restrict__ Wlbv,
                                                   float* __restrict__ Wf)
{
    const int c0 = blockIdx.x * 64;
    const int br = blockIdx.y;
    const int b  = blockIdx.z;

    __shared__ short Al[64][72];   // WlWv[c][k] bf16
    __shared__ short Bl[64][72];   // KX[m][k] bf16

    const int tid  = threadIdx.x;
    const int lane = tid & 63;
    const int w    = tid >> 6;
    const int lrow = lane & 15;
    const int lkg  = lane >> 4;

    const float* kxb = KX + ((size_t)b * 3 + br) * M_ * C_;

    f32x4 acc[4] = {{0.f,0.f,0.f,0.f},{0.f,0.f,0.f,0.f},{0.f,0.f,0.f,0.f},{0.f,0.f,0.f,0.f}};

    for (int kc = 0; kc < C_ / 64; ++kc) {
        const int k0 = kc * 64;
        __syncthreads();
        #pragma unroll
        for (int i = 0; i < 4; ++i) {
            int f = tid + i * 256;
            int r = f >> 4, c4 = (f & 15) * 4;
            f32x4 v = *reinterpret_cast<const f32x4*>(&WlWv[(size_t)(c0 + r) * C_ + k0 + c4]);
            short4 s;
            s.x = f2bf(v[0]); s.y = f2bf(v[1]); s.z = f2bf(v[2]); s.w = f2bf(v[3]);
            *reinterpret_cast<short4*>(&Al[r][c4]) = s;
        }
        #pragma unroll
        for (int i = 0; i < 4; ++i) {
            int f = tid + i * 256;
            int r = f >> 4, c4 = (f & 15) * 4;
            f32x4 v = *reinterpret_cast<const f32x4*>(&kxb[(size_t)r * C_ + k0 + c4]);
            short4 s;
            s.x = f2bf(v[0]); s.y = f2bf(v[1]); s.z = f2bf(v[2]); s.w = f2bf(v[3]);
            *reinterpret_cast<short4*>(&Bl[r][c4]) = s;
        }
        __syncthreads();
        #pragma unroll
        for (int ks = 0; ks < 2; ++ks) {
            bf16x8 a = *reinterpret_cast<const bf16x8*>(&Al[w * 16 + lrow][ks * 32 + lkg * 8]);
            #pragma unroll
            for (int ns = 0; ns < 4; ++ns) {
                bf16x8 bx = *reinterpret_cast<const bf16x8*>(&Bl[ns * 16 + lrow][ks * 32 + lkg * 8]);
                acc[ns] = __builtin_amdgcn_mfma_f32_16x16x32_bf16(a, bx, acc[ns], 0, 0, 0);
            }
        }
    }

    const float* ks_ = Ksum + ((size_t)b * 3 + br) * M_;
    float* wfb = Wf + (((size_t)b * 3 + br) * C_) * M_;
    #pragma unroll
    for (int r = 0; r < 4; ++r) {
        int c = c0 + w * 16 + lkg * 4 + r;
        float wb = Wlbv[c];
        #pragma unroll
        for (int ns = 0; ns < 4; ++ns) {
            int m = ns * 16 + lrow;
            wfb[(size_t)c * M_ + m] = acc[ns][r] + ks_[m] * wb;
        }
    }
}

// ---------------------------------------------------------------------------
// Kernel 6 (MFMA): out = x + gamma*(bl + sum_br norm_br * (Wf_br @ QT^T)).
// ---------------------------------------------------------------------------
__global__ __launch_bounds__(256) void final_mfma_kernel(
    const short* __restrict__ QT, const float* __restrict__ Wf,
    const float* __restrict__ Ksum, const float* __restrict__ x,
    const float* __restrict__ bl, const float* __restrict__ gamma,
    float* __restrict__ out)
{
    const int n0 = blockIdx.x * 64;
    const int c0 = blockIdx.y * 64;
    const int b  = blockIdx.z;

    __shared__ short Qs[64][72];      // [n][m] bf16
    __shared__ short Wfs[3][64][72];  // [br][c][m] bf16
    __shared__ float norms[3][64];
    __shared__ float ksef[3][64];

    const int tid  = threadIdx.x;
    const int lane = tid & 63;
    const int w    = tid >> 6;
    const int lrow = lane & 15;
    const int lkg  = lane >> 4;

    const short* qtb = QT + (size_t)b * N_ * M_;
    #pragma unroll
    for (int i = 0; i < 2; ++i) {
        int f = tid + i * 256;
        int r = f >> 3, m8 = (f & 7) * 8;
        *reinterpret_cast<int4*>(&Qs[r][m8]) =
            *reinterpret_cast<const int4*>(&qtb[(size_t)(n0 + r) * M_ + m8]);
    }
    #pragma unroll
    for (int br = 0; br < 3; ++br) {
        const float* wfb = Wf + (((size_t)b * 3 + br) * C_ + c0) * M_;
        #pragma unroll
        for (int i = 0; i < 4; ++i) {
            int f = tid + i * 256;
            int r = f >> 4, m4 = (f & 15) * 4;
            float4 v = *reinterpret_cast<const float4*>(&wfb[(size_t)r * M_ + m4]);
            short4 s;
            s.x = f2bf(v.x); s.y = f2bf(v.y); s.z = f2bf(v.z); s.w = f2bf(v.w);
            *reinterpret_cast<short4*>(&Wfs[br][r][m4]) = s;
        }
    }
    if (tid < 192) {
        int br = tid >> 6, m = tid & 63;
        ksef[br][m] = Ksum[((size_t)b * 3 + br) * M_ + m] + EPS_;
    }
    __syncthreads();
    if (tid < 192) {
        int br = tid >> 6, n = tid & 63;
        float s = 0.f;
        #pragma unroll 16
        for (int m = 0; m < 64; ++m) s = fmaf(bf2f(Qs[n][m]), ksef[br][m], s);
        norms[br][n] = 1.0f / s;
    }
    __syncthreads();

    f32x4 tot[4] = {{0.f,0.f,0.f,0.f},{0.f,0.f,0.f,0.f},{0.f,0.f,0.f,0.f},{0.f,0.f,0.f,0.f}};
    for (int br = 0; br < 3; ++br) {
        f32x4 acc[4] = {{0.f,0.f,0.f,0.f},{0.f,0.f,0.f,0.f},{0.f,0.f,0.f,0.f},{0.f,0.f,0.f,0.f}};
        #pragma unroll
        for (int ks = 0; ks < 2; ++ks) {
            bf16x8 a = *reinterpret_cast<const bf16x8*>(&Wfs[br][w * 16 + lrow][ks * 32 + lkg * 8]);
            #pragma unroll
            for (int ns = 0; ns < 4; ++ns) {
                bf16x8 bq = *reinterpret_cast<const bf16x8*>(&Qs[ns * 16 + lrow][ks * 32 + lkg * 8]);
                acc[ns] = __builtin_amdgcn_mfma_f32_16x16x32_bf16(a, bq, acc[ns], 0, 0, 0);
            }
        }
        #pragma unroll
        for (int ns = 0; ns < 4; ++ns) {
            float nf = norms[br][ns * 16 + lrow];
            #pragma unroll
            for (int r = 0; r < 4; ++r) tot[ns][r] = fmaf(nf, acc[ns][r], tot[ns][r]);
        }
    }

    const float g = gamma[0];
    const float* xb = x + (size_t)b * C_ * N_;
    float* ob = out + (size_t)b * C_ * N_;
    #pragma unroll
    for (int r = 0; r < 4; ++r) {
        int c = c0 + w * 16 + lkg * 4 + r;
        float blc = bl[c];
        #pragma unroll
        for (int ns = 0; ns < 4; ++ns) {
            int n = n0 + ns * 16 + lrow;
            ob[(size_t)c * N_ + n] = fmaf(g, tot[ns][r] + blc, xb[(size_t)c * N_ + n]);
        }
    }
}

// ---------------------------------------------------------------------------
extern "C" void kernel_launch(void* const* d_in, const int* in_sizes, int n_in,
                              void* d_out, int out_size, void* d_ws, size_t ws_size,
                              hipStream_t stream)
{
    const float* x   = (const float*)d_in[0];
    const float* y   = (const float*)d_in[1];
    const float* z   = (const float*)d_in[2];
    const float* Wq  = (const float*)d_in[3];
    const float* bq  = (const float*)d_in[4];
    const float* Wk1 = (const float*)d_in[5];
    const float* bk1 = (const float*)d_in[6];
    const float* Wk2 = (const float*)d_in[7];
    const float* bk2 = (const float*)d_in[8];
    const float* Wk3 = (const float*)d_in[9];
    const float* bk3 = (const float*)d_in[10];
    const float* Wv  = (const float*)d_in[11];
    const float* bv  = (const float*)d_in[12];
    const float* Wl  = (const float*)d_in[13];
    const float* bl  = (const float*)d_in[14];
    const float* gamma = (const float*)d_in[15];
    float* out = (float*)d_out;

    // workspace layout (~35 MB of the 256 MiB d_ws).
    float* ws = (float*)d_ws;
    const size_t QSZ  = (size_t)B_ * M_ * N_;        // 2,097,152 elements
    const size_t BMC  = (size_t)B_ * M_ * C_;        //   262,144
    short* QTs   = (short*)ws;                        // [B][N][M] bf16
    short* Kbuf3 = QTs + QSZ;                         // [3][B][M][N] bf16 (12 MB)
    float* fbase = ws + 2 * QSZ;                      // float region
    float* KX    = fbase;                             // [B][3][M][C]
    float* Ksum  = KX + 3 * BMC;                      // [B][3][M]
    float* WlWv  = Ksum + (size_t)B_ * 3 * M_;        // [C][C]
    float* Wlbv  = WlWv + (size_t)C_ * C_;            // [C]
    float* Ksumpart = Wlbv + C_;                      // [3][B][64][M]
    float* KXpart3  = Ksumpart + (size_t)3 * B_ * 64 * M_;  // [3][4][B][M][C] (12MB)
    float* WlWvPart = KXpart3;                        // alias (4MB, dead before wlwv)
    float* Wf   = KXpart3;                            // alias (3MB, after kx3_reduce)
    short* Wbf  = (short*)(KXpart3 + (size_t)3 * NCHUNK_ * BMC);  // [4][M][C] bf16

    dim3 blk(256);

    // 0) one-time bf16 conversion of the 4 feature weight matrices
    prep_w<<<dim3((M_ * C_ + 255) / 256), blk, 0, stream>>>(Wq, Wk1, Wk2, Wk3, Wbf);
    // 1) feature GEMMs: y=0 computes Q+K1 off one x staging; y=1,2 -> K2,K3
    feat_mfma<<<dim3(N_ / 64, 3, B_), blk, 0, stream>>>(
        x, y, z, Wbf, bq, bk1, bk2, bk3, QTs, Kbuf3, Ksumpart);
    // 2) finalize ksum for all branches
    ksum_finalize<<<dim3((3 * B_ * M_ + 255) / 256), blk, 0, stream>>>(Ksumpart, Ksum);
    // 3) KX for all branches in one pass (x staged once per tile)
    kx3_mfma<<<dim3(C_ / 32, NCHUNK_, B_), blk, 0, stream>>>(Kbuf3, x, KXpart3);
    kx3_reduce<<<dim3((int)((3 * BMC + 255) / 256)), blk, 0, stream>>>(KXpart3, KX);

    // 4) batch-independent fused weights (partials alias KXpart3 — after kx3_reduce)
    wlwv_mfma<<<dim3(C_ / 64, C_ / 64, 4), blk, 0, stream>>>(Wl, Wv, WlWvPart);
    wlwv_reduce<<<dim3(((int)((size_t)C_ * C_) + 255) / 256), blk, 0, stream>>>(WlWvPart, WlWv);
    wlbv_kernel<<<dim3((C_ + 255) / 256), blk, 0, stream>>>(Wl, bv, Wlbv);
    // 5) per-batch fused weights
    wfused_mfma<<<dim3(C_ / 64, 3, B_), blk, 0, stream>>>(WlWv, KX, Ksum, Wlbv, Wf);
    // 6) final: norms + MFMA GEMM + bias + residual
    final_mfma_kernel<<<dim3(N_ / 64, C_ / 64, B_), blk, 0, stream>>>(
        QTs, Wf, Ksum, x, bl, gamma, out);
}